// Round 1
// baseline (210.787 us; speedup 1.0000x reference)
//
#include <hip/hip_runtime.h>
#include <math.h>

// Problem constants (fixed shapes from setup_inputs)
#define BB 4
#define MM 4096
#define DD 32
#define NPTS (BB*MM)        // 16384 fit points
#define TOTELEM (NPTS*DD)   // 524288 floats in X_fit
#define NBINS 4096
#define CAP 4096

// ws layout (bytes)
#define HIST_OFF   0        // 4096 u32
#define SUM_OFF    16384    // 4 f32
#define SUMSQ_OFF  16400    // 4 f32
#define CCNT_OFF   16416    // 4 u32
#define TBIN_OFF   16432    // 4 i32
#define BASE_OFF   16448    // 4 u32
#define SVAL_OFF   16464    // 4 f32
#define COEF_OFF   16480    // 4 f32
#define ZERO_BYTES 16512
#define CAND_OFF   16512    // 4*4096 f32
#define NMU2_OFF   82048    // 16384 f32

__device__ __forceinline__ int bin_of(float x) {
    int b = (int)floorf((x + 2.0f) * 1024.0f);
    return b < 0 ? 0 : (b > (NBINS - 1) ? (NBINS - 1) : b);
}

// K1: per-batch sum/sumsq, global histogram of X_fit, nmu2 per fit point
__global__ __launch_bounds__(256) void k_stats(
    const float* __restrict__ Xf, unsigned int* __restrict__ hist,
    float* __restrict__ sums, float* __restrict__ sumsqs, float* __restrict__ nmu2)
{
    __shared__ unsigned int lh[NBINS];
    __shared__ float rs[256], rs2[256];
    int tid = threadIdx.x;
    for (int i = tid; i < NBINS; i += 256) lh[i] = 0;
    __syncthreads();

    int p = blockIdx.x * 256 + tid;          // fit-point index, block is within one batch
    int b = p >> 12;
    const float4* src = (const float4*)(Xf + (size_t)p * DD);
    float s = 0.f, s2 = 0.f;
    #pragma unroll
    for (int j = 0; j < 8; j++) {
        float4 v = src[j];
        float xs[4] = {v.x, v.y, v.z, v.w};
        #pragma unroll
        for (int c = 0; c < 4; c++) {
            float x = xs[c];
            s += x;
            s2 = fmaf(x, x, s2);
            atomicAdd(&lh[bin_of(x)], 1u);
        }
    }
    nmu2[p] = s2;
    rs[tid] = s; rs2[tid] = s2;
    __syncthreads();
    for (int off = 128; off > 0; off >>= 1) {
        if (tid < off) { rs[tid] += rs[tid + off]; rs2[tid] += rs2[tid + off]; }
        __syncthreads();
    }
    if (tid == 0) { atomicAdd(&sums[b], rs[0]); atomicAdd(&sumsqs[b], rs2[0]); }
    __syncthreads();
    for (int i = tid; i < NBINS; i += 256)
        if (lh[i]) atomicAdd(&hist[i], lh[i]);
}

// K2: scan histogram, locate bin + cumulative base for each target rank
__global__ __launch_bounds__(256) void k_findbins(
    const unsigned int* __restrict__ hist, int* __restrict__ tbin,
    unsigned int* __restrict__ basec)
{
    __shared__ unsigned int chunk[256];
    int tid = threadIdx.x;
    unsigned int s = 0;
    for (int i = 0; i < 16; i++) s += hist[tid * 16 + i];
    chunk[tid] = s;
    __syncthreads();
    if (tid == 0) {
        unsigned int run = 0;
        for (int i = 0; i < 256; i++) { unsigned int t = chunk[i]; chunk[i] = run; run += t; }
    }
    __syncthreads();
    const unsigned int ranks[4] = {131071u, 131072u, 393215u, 393216u};
    unsigned int cum = chunk[tid];
    for (int i = 0; i < 16; i++) {
        int bin = tid * 16 + i;
        unsigned int c = hist[bin];
        #pragma unroll
        for (int r = 0; r < 4; r++) {
            if (cum <= ranks[r] && ranks[r] < cum + c) { tbin[r] = bin; basec[r] = cum; }
        }
        cum += c;
    }
}

// K3: collect candidate values falling in each target bin
__global__ __launch_bounds__(256) void k_collect(
    const float* __restrict__ Xf, const int* __restrict__ tbin,
    unsigned int* __restrict__ ccnt, float* __restrict__ cand)
{
    int gid = blockIdx.x * 256 + threadIdx.x;   // 131072 threads, 4 floats each
    float4 v = ((const float4*)Xf)[gid];
    int t0 = tbin[0], t1 = tbin[1], t2 = tbin[2], t3 = tbin[3];
    float xs[4] = {v.x, v.y, v.z, v.w};
    #pragma unroll
    for (int c = 0; c < 4; c++) {
        int bin = bin_of(xs[c]);
        int tb[4] = {t0, t1, t2, t3};
        #pragma unroll
        for (int r = 0; r < 4; r++) {
            if (bin == tb[r]) {
                unsigned int pos = atomicAdd(&ccnt[r], 1u);
                if (pos < CAP) cand[r * CAP + pos] = xs[c];
            }
        }
    }
}

// K4: exact selection within candidates, then bandwidth -> coef[b] = log2(e)/bw
__global__ __launch_bounds__(256) void k_select(
    const float* __restrict__ cand, const unsigned int* __restrict__ ccnt,
    const unsigned int* __restrict__ basec, float* svals,
    const float* __restrict__ sums, const float* __restrict__ sumsqs,
    float* __restrict__ coef)
{
    __shared__ float cv[CAP];
    const unsigned int ranks[4] = {131071u, 131072u, 393215u, 393216u};
    int tid = threadIdx.x;
    for (int r = 0; r < 4; r++) {
        unsigned int C = ccnt[r]; if (C > CAP) C = CAP;
        unsigned int k = ranks[r] - basec[r];
        for (unsigned int i = tid; i < C; i += 256) cv[i] = cand[r * CAP + i];
        __syncthreads();
        for (unsigned int i = tid; i < C; i += 256) {
            float v = cv[i];
            unsigned int lt = 0, eq = 0;
            for (unsigned int j = 0; j < C; j++) {
                float w = cv[j];
                lt += (w < v) ? 1u : 0u;
                eq += (w == v) ? 1u : 0u;
            }
            if (lt <= k && k < lt + eq) svals[r] = v;   // all matching writers write same value
        }
        __syncthreads();
    }
    if (tid == 0) {
        float s0 = svals[0], s1 = svals[1], s2 = svals[2], s3 = svals[3];
        double q25 = (double)s0 + 0.75 * ((double)s1 - (double)s0);
        double q75 = (double)s2 + 0.25 * ((double)s3 - (double)s2);
        double q = q75 - q25;
        for (int b = 0; b < BB; b++) {
            double n = (double)(MM * DD);
            double sm = (double)sums[b], sq = (double)sumsqs[b];
            double var = (sq - sm * sm / n) / (n - 1.0);
            double sd = sqrt(var);
            double mn = sd < q / 1.34 ? sd : q / 1.34;
            double bw = 0.9 * mn / 5.278031643091577;   // 4096**0.2
            coef[b] = (float)(1.4426950408889634 / bw); // log2(e)/bw
        }
    }
}

// K5: main KDE kernel. One thread = one query; loop over a 512-wide m chunk.
__global__ __launch_bounds__(256) void k_kde(
    const float* __restrict__ Xq, const float* __restrict__ Xf,
    const float* __restrict__ nmu2, const float* __restrict__ coef,
    float* __restrict__ out)
{
    int tid = threadIdx.x;
    int qg = blockIdx.x;            // 0..63
    int b = qg >> 4;                // 16 query-groups per batch
    int q_idx = qg * 256 + tid;     // 0..16383
    const float4* qp = (const float4*)(Xq + (size_t)q_idx * DD);
    float q[DD];
    #pragma unroll
    for (int j = 0; j < 8; j++) {
        float4 v = qp[j];
        q[4 * j + 0] = v.x; q[4 * j + 1] = v.y; q[4 * j + 2] = v.z; q[4 * j + 3] = v.w;
    }
    float nx2 = 0.f;
    #pragma unroll
    for (int j = 0; j < DD; j++) nx2 = fmaf(q[j], q[j], nx2);

    float c = coef[b];
    int m0 = blockIdx.y * 512;
    const float* fb = Xf + ((size_t)b * MM + m0) * DD;   // wave-uniform base
    const float* nm = nmu2 + b * MM + m0;

    float acc = 0.f;
    for (int mm = 0; mm < 512; ++mm) {
        const float4* mu = (const float4*)(fb + (size_t)mm * DD);  // uniform address -> s_load
        float t0 = 0.f, t1 = 0.f, t2 = 0.f, t3 = 0.f;
        #pragma unroll
        for (int j = 0; j < 8; j++) {
            float4 mv = mu[j];
            t0 = fmaf(q[4 * j + 0], mv.x, t0);
            t1 = fmaf(q[4 * j + 1], mv.y, t1);
            t2 = fmaf(q[4 * j + 2], mv.z, t2);
            t3 = fmaf(q[4 * j + 3], mv.w, t3);
        }
        float dot = (t0 + t1) + (t2 + t3);
        float dist = nx2 + nm[mm] - 2.0f * dot;
        acc += exp2f(-dist * c);
    }
    atomicAdd(&out[q_idx], acc);
}

extern "C" void kernel_launch(void* const* d_in, const int* in_sizes, int n_in,
                              void* d_out, int out_size, void* d_ws, size_t ws_size,
                              hipStream_t stream) {
    const float* Xq = (const float*)d_in[0];
    const float* Xf = (const float*)d_in[1];
    float* out = (float*)d_out;
    char* ws = (char*)d_ws;

    unsigned int* hist  = (unsigned int*)(ws + HIST_OFF);
    float* sums         = (float*)(ws + SUM_OFF);
    float* sumsqs       = (float*)(ws + SUMSQ_OFF);
    unsigned int* ccnt  = (unsigned int*)(ws + CCNT_OFF);
    int* tbin           = (int*)(ws + TBIN_OFF);
    unsigned int* basec = (unsigned int*)(ws + BASE_OFF);
    float* svals        = (float*)(ws + SVAL_OFF);
    float* coef         = (float*)(ws + COEF_OFF);
    float* cand         = (float*)(ws + CAND_OFF);
    float* nmu2         = (float*)(ws + NMU2_OFF);

    hipMemsetAsync(ws, 0, ZERO_BYTES, stream);
    hipMemsetAsync(d_out, 0, (size_t)out_size * sizeof(float), stream);

    k_stats<<<NPTS / 256, 256, 0, stream>>>(Xf, hist, sums, sumsqs, nmu2);
    k_findbins<<<1, 256, 0, stream>>>(hist, tbin, basec);
    k_collect<<<TOTELEM / (256 * 4), 256, 0, stream>>>(Xf, tbin, ccnt, cand);
    k_select<<<1, 256, 0, stream>>>(cand, ccnt, basec, svals, sums, sumsqs, coef);
    k_kde<<<dim3(64, 8), 256, 0, stream>>>(Xq, Xf, nmu2, coef, out);
}

// Round 2
// 202.056 us; speedup vs baseline: 1.0432x; 1.0432x over previous
//
#include <hip/hip_runtime.h>
#include <math.h>

// Problem constants (fixed shapes from setup_inputs)
#define BB 4
#define MM 4096
#define DD 32
#define NPTS (BB*MM)        // 16384 fit points
#define TOTELEM (NPTS*DD)   // 524288 floats in X_fit
#define NBINS 4096
#define CAP 4096

// ws layout (bytes)
#define HIST_OFF   0        // 4096 u32
#define SUM_OFF    16384    // 4 f32
#define SUMSQ_OFF  16400    // 4 f32
#define CCNT_OFF   16416    // 4 u32
#define TBIN_OFF   16432    // 4 i32
#define BASE_OFF   16448    // 4 u32
#define SVAL_OFF   16464    // 4 f32
#define COEF_OFF   16480    // 4 f32
#define ZERO_BYTES 16512
#define CAND_OFF   16512    // 4*4096 f32
#define NMU2_OFF   82048    // 16384 f32

__device__ __forceinline__ int bin_of(float x) {
    int b = (int)floorf((x + 2.0f) * 1024.0f);
    return b < 0 ? 0 : (b > (NBINS - 1) ? (NBINS - 1) : b);
}

// K1: per-batch sum/sumsq, global histogram of X_fit, nmu2 per fit point.
// 256 blocks x 256 threads; each thread owns 8 consecutive floats (a quarter
// of one fit point); quad lanes combine via shfl_xor for nmu2.
__global__ __launch_bounds__(256) void k_stats(
    const float* __restrict__ Xf, unsigned int* __restrict__ hist,
    float* __restrict__ sums, float* __restrict__ sumsqs, float* __restrict__ nmu2)
{
    __shared__ unsigned int lh[NBINS];
    __shared__ float rs[256], rs2[256];
    int tid = threadIdx.x;
    for (int i = tid; i < NBINS; i += 256) lh[i] = 0;
    __syncthreads();

    int t = blockIdx.x * 256 + tid;          // 0..65535, quarter-point index
    int b = blockIdx.x >> 6;                 // 64 blocks per batch
    const float4* src = (const float4*)Xf + (size_t)t * 2;
    float4 v0 = src[0], v1 = src[1];
    float xs[8] = {v0.x, v0.y, v0.z, v0.w, v1.x, v1.y, v1.z, v1.w};
    float s = 0.f, s2 = 0.f;
    #pragma unroll
    for (int c = 0; c < 8; c++) {
        float x = xs[c];
        s += x;
        s2 = fmaf(x, x, s2);
        atomicAdd(&lh[bin_of(x)], 1u);
    }
    // quad-combine for nmu2 (lanes 4k..4k+3 hold quarters of point t>>2)
    float r = s2;
    r += __shfl_xor(r, 1);
    r += __shfl_xor(r, 2);
    if ((t & 3) == 0) nmu2[t >> 2] = r;

    rs[tid] = s; rs2[tid] = s2;
    __syncthreads();
    for (int off = 128; off > 0; off >>= 1) {
        if (tid < off) { rs[tid] += rs[tid + off]; rs2[tid] += rs2[tid + off]; }
        __syncthreads();
    }
    if (tid == 0) { atomicAdd(&sums[b], rs[0]); atomicAdd(&sumsqs[b], rs2[0]); }
    __syncthreads();
    for (int i = tid; i < NBINS; i += 256)
        if (lh[i]) atomicAdd(&hist[i], lh[i]);
}

// K2: scan histogram, locate bin + cumulative base for each target rank
__global__ __launch_bounds__(256) void k_findbins(
    const unsigned int* __restrict__ hist, int* __restrict__ tbin,
    unsigned int* __restrict__ basec)
{
    __shared__ unsigned int chunk[256];
    int tid = threadIdx.x;
    unsigned int s = 0;
    for (int i = 0; i < 16; i++) s += hist[tid * 16 + i];
    chunk[tid] = s;
    __syncthreads();
    if (tid == 0) {
        unsigned int run = 0;
        for (int i = 0; i < 256; i++) { unsigned int t = chunk[i]; chunk[i] = run; run += t; }
    }
    __syncthreads();
    const unsigned int ranks[4] = {131071u, 131072u, 393215u, 393216u};
    unsigned int cum = chunk[tid];
    for (int i = 0; i < 16; i++) {
        int bin = tid * 16 + i;
        unsigned int c = hist[bin];
        #pragma unroll
        for (int r = 0; r < 4; r++) {
            if (cum <= ranks[r] && ranks[r] < cum + c) { tbin[r] = bin; basec[r] = cum; }
        }
        cum += c;
    }
}

// K3: collect candidate values falling in each target bin
__global__ __launch_bounds__(256) void k_collect(
    const float* __restrict__ Xf, const int* __restrict__ tbin,
    unsigned int* __restrict__ ccnt, float* __restrict__ cand)
{
    int gid = blockIdx.x * 256 + threadIdx.x;   // 131072 threads, 4 floats each
    float4 v = ((const float4*)Xf)[gid];
    int t0 = tbin[0], t1 = tbin[1], t2 = tbin[2], t3 = tbin[3];
    float xs[4] = {v.x, v.y, v.z, v.w};
    #pragma unroll
    for (int c = 0; c < 4; c++) {
        int bin = bin_of(xs[c]);
        int tb[4] = {t0, t1, t2, t3};
        #pragma unroll
        for (int r = 0; r < 4; r++) {
            if (bin == tb[r]) {
                unsigned int pos = atomicAdd(&ccnt[r], 1u);
                if (pos < CAP) cand[r * CAP + pos] = xs[c];
            }
        }
    }
}

// K4: exact selection within candidates, then bandwidth -> coef[b] = log2(e)/bw
__global__ __launch_bounds__(256) void k_select(
    const float* __restrict__ cand, const unsigned int* __restrict__ ccnt,
    const unsigned int* __restrict__ basec, float* svals,
    const float* __restrict__ sums, const float* __restrict__ sumsqs,
    float* __restrict__ coef)
{
    __shared__ float cv[CAP];
    const unsigned int ranks[4] = {131071u, 131072u, 393215u, 393216u};
    int tid = threadIdx.x;
    for (int r = 0; r < 4; r++) {
        unsigned int C = ccnt[r]; if (C > CAP) C = CAP;
        unsigned int k = ranks[r] - basec[r];
        for (unsigned int i = tid; i < C; i += 256) cv[i] = cand[r * CAP + i];
        __syncthreads();
        for (unsigned int i = tid; i < C; i += 256) {
            float v = cv[i];
            unsigned int lt = 0, eq = 0;
            for (unsigned int j = 0; j < C; j++) {
                float w = cv[j];
                lt += (w < v) ? 1u : 0u;
                eq += (w == v) ? 1u : 0u;
            }
            if (lt <= k && k < lt + eq) svals[r] = v;   // all matching writers write same value
        }
        __syncthreads();
    }
    if (tid == 0) {
        float s0 = svals[0], s1 = svals[1], s2 = svals[2], s3 = svals[3];
        double q25 = (double)s0 + 0.75 * ((double)s1 - (double)s0);
        double q75 = (double)s2 + 0.25 * ((double)s3 - (double)s2);
        double q = q75 - q25;
        for (int b = 0; b < BB; b++) {
            double n = (double)(MM * DD);
            double sm = (double)sums[b], sq = (double)sumsqs[b];
            double var = (sq - sm * sm / n) / (n - 1.0);
            double sd = sqrt(var);
            double mn = sd < q / 1.34 ? sd : q / 1.34;
            double bw = 0.9 * mn / 5.278031643091577;   // 4096**0.2
            coef[b] = (float)(1.4426950408889634 / bw); // log2(e)/bw
        }
    }
}

// K5: main KDE kernel. One thread = one query; 128-wide m chunk per block.
// grid (64, 32) = 2048 blocks -> 8 blocks/CU, 32 waves/CU. Fit-point loads
// are wave-uniform -> scalar loads; 2 m-points in flight for ILP.
__global__ __launch_bounds__(256) void k_kde(
    const float* __restrict__ Xq, const float* __restrict__ Xf,
    const float* __restrict__ nmu2, const float* __restrict__ coef,
    float* __restrict__ out)
{
    int tid = threadIdx.x;
    int qg = blockIdx.x;            // 0..63
    int b = qg >> 4;                // 16 query-groups per batch
    int q_idx = qg * 256 + tid;     // 0..16383
    const float4* qp = (const float4*)(Xq + (size_t)q_idx * DD);
    float4 q0 = qp[0], q1 = qp[1], q2 = qp[2], q3 = qp[3];
    float4 q4 = qp[4], q5 = qp[5], q6 = qp[6], q7 = qp[7];

    float nx2 = 0.f;
    {
        float a0 = 0.f, a1 = 0.f, a2 = 0.f, a3 = 0.f;
        a0 = fmaf(q0.x,q0.x,fmaf(q1.x,q1.x,fmaf(q2.x,q2.x,fmaf(q3.x,q3.x,
             fmaf(q4.x,q4.x,fmaf(q5.x,q5.x,fmaf(q6.x,q6.x,q7.x*q7.x)))))));
        a1 = fmaf(q0.y,q0.y,fmaf(q1.y,q1.y,fmaf(q2.y,q2.y,fmaf(q3.y,q3.y,
             fmaf(q4.y,q4.y,fmaf(q5.y,q5.y,fmaf(q6.y,q6.y,q7.y*q7.y)))))));
        a2 = fmaf(q0.z,q0.z,fmaf(q1.z,q1.z,fmaf(q2.z,q2.z,fmaf(q3.z,q3.z,
             fmaf(q4.z,q4.z,fmaf(q5.z,q5.z,fmaf(q6.z,q6.z,q7.z*q7.z)))))));
        a3 = fmaf(q0.w,q0.w,fmaf(q1.w,q1.w,fmaf(q2.w,q2.w,fmaf(q3.w,q3.w,
             fmaf(q4.w,q4.w,fmaf(q5.w,q5.w,fmaf(q6.w,q6.w,q7.w*q7.w)))))));
        nx2 = (a0 + a1) + (a2 + a3);
    }

    float c = coef[b];
    float c2 = 2.0f * c;
    float pre = -c * nx2;           // arg = c2*dot + (pre - c*nm)
    int m0 = blockIdx.y * 128;
    const float* fb = Xf + ((size_t)b * MM + m0) * DD;   // wave-uniform base
    const float* nm = nmu2 + b * MM + m0;

    float acc = 0.f;
    for (int mm = 0; mm < 128; mm += 2) {
        const float4* muA = (const float4*)(fb + (size_t)mm * DD);  // uniform -> s_load
        const float4* muB = muA + 8;
        float t0 = 0.f, t1 = 0.f, t2 = 0.f, t3 = 0.f;
        float u0 = 0.f, u1 = 0.f, u2 = 0.f, u3 = 0.f;
        float4 a0 = muA[0], a1 = muA[1], a2 = muA[2], a3 = muA[3];
        float4 a4 = muA[4], a5 = muA[5], a6 = muA[6], a7 = muA[7];
        float4 b0 = muB[0], b1 = muB[1], b2 = muB[2], b3 = muB[3];
        float4 b4 = muB[4], b5 = muB[5], b6 = muB[6], b7 = muB[7];

        t0 = fmaf(q0.x,a0.x,t0); t1 = fmaf(q0.y,a0.y,t1); t2 = fmaf(q0.z,a0.z,t2); t3 = fmaf(q0.w,a0.w,t3);
        u0 = fmaf(q0.x,b0.x,u0); u1 = fmaf(q0.y,b0.y,u1); u2 = fmaf(q0.z,b0.z,u2); u3 = fmaf(q0.w,b0.w,u3);
        t0 = fmaf(q1.x,a1.x,t0); t1 = fmaf(q1.y,a1.y,t1); t2 = fmaf(q1.z,a1.z,t2); t3 = fmaf(q1.w,a1.w,t3);
        u0 = fmaf(q1.x,b1.x,u0); u1 = fmaf(q1.y,b1.y,u1); u2 = fmaf(q1.z,b1.z,u2); u3 = fmaf(q1.w,b1.w,u3);
        t0 = fmaf(q2.x,a2.x,t0); t1 = fmaf(q2.y,a2.y,t1); t2 = fmaf(q2.z,a2.z,t2); t3 = fmaf(q2.w,a2.w,t3);
        u0 = fmaf(q2.x,b2.x,u0); u1 = fmaf(q2.y,b2.y,u1); u2 = fmaf(q2.z,b2.z,u2); u3 = fmaf(q2.w,b2.w,u3);
        t0 = fmaf(q3.x,a3.x,t0); t1 = fmaf(q3.y,a3.y,t1); t2 = fmaf(q3.z,a3.z,t2); t3 = fmaf(q3.w,a3.w,t3);
        u0 = fmaf(q3.x,b3.x,u0); u1 = fmaf(q3.y,b3.y,u1); u2 = fmaf(q3.z,b3.z,u2); u3 = fmaf(q3.w,b3.w,u3);
        t0 = fmaf(q4.x,a4.x,t0); t1 = fmaf(q4.y,a4.y,t1); t2 = fmaf(q4.z,a4.z,t2); t3 = fmaf(q4.w,a4.w,t3);
        u0 = fmaf(q4.x,b4.x,u0); u1 = fmaf(q4.y,b4.y,u1); u2 = fmaf(q4.z,b4.z,u2); u3 = fmaf(q4.w,b4.w,u3);
        t0 = fmaf(q5.x,a5.x,t0); t1 = fmaf(q5.y,a5.y,t1); t2 = fmaf(q5.z,a5.z,t2); t3 = fmaf(q5.w,a5.w,t3);
        u0 = fmaf(q5.x,b5.x,u0); u1 = fmaf(q5.y,b5.y,u1); u2 = fmaf(q5.z,b5.z,u2); u3 = fmaf(q5.w,b5.w,u3);
        t0 = fmaf(q6.x,a6.x,t0); t1 = fmaf(q6.y,a6.y,t1); t2 = fmaf(q6.z,a6.z,t2); t3 = fmaf(q6.w,a6.w,t3);
        u0 = fmaf(q6.x,b6.x,u0); u1 = fmaf(q6.y,b6.y,u1); u2 = fmaf(q6.z,b6.z,u2); u3 = fmaf(q6.w,b6.w,u3);
        t0 = fmaf(q7.x,a7.x,t0); t1 = fmaf(q7.y,a7.y,t1); t2 = fmaf(q7.z,a7.z,t2); t3 = fmaf(q7.w,a7.w,t3);
        u0 = fmaf(q7.x,b7.x,u0); u1 = fmaf(q7.y,b7.y,u1); u2 = fmaf(q7.z,b7.z,u2); u3 = fmaf(q7.w,b7.w,u3);

        float dotA = (t0 + t1) + (t2 + t3);
        float dotB = (u0 + u1) + (u2 + u3);
        float argA = fmaf(c2, dotA, fmaf(-c, nm[mm],     pre));
        float argB = fmaf(c2, dotB, fmaf(-c, nm[mm + 1], pre));
        acc += exp2f(argA);
        acc += exp2f(argB);
    }
    atomicAdd(&out[q_idx], acc);
}

extern "C" void kernel_launch(void* const* d_in, const int* in_sizes, int n_in,
                              void* d_out, int out_size, void* d_ws, size_t ws_size,
                              hipStream_t stream) {
    const float* Xq = (const float*)d_in[0];
    const float* Xf = (const float*)d_in[1];
    float* out = (float*)d_out;
    char* ws = (char*)d_ws;

    unsigned int* hist  = (unsigned int*)(ws + HIST_OFF);
    float* sums         = (float*)(ws + SUM_OFF);
    float* sumsqs       = (float*)(ws + SUMSQ_OFF);
    unsigned int* ccnt  = (unsigned int*)(ws + CCNT_OFF);
    int* tbin           = (int*)(ws + TBIN_OFF);
    unsigned int* basec = (unsigned int*)(ws + BASE_OFF);
    float* svals        = (float*)(ws + SVAL_OFF);
    float* coef         = (float*)(ws + COEF_OFF);
    float* cand         = (float*)(ws + CAND_OFF);
    float* nmu2         = (float*)(ws + NMU2_OFF);

    hipMemsetAsync(ws, 0, ZERO_BYTES, stream);
    hipMemsetAsync(d_out, 0, (size_t)out_size * sizeof(float), stream);

    k_stats<<<256, 256, 0, stream>>>(Xf, hist, sums, sumsqs, nmu2);
    k_findbins<<<1, 256, 0, stream>>>(hist, tbin, basec);
    k_collect<<<TOTELEM / (256 * 4), 256, 0, stream>>>(Xf, tbin, ccnt, cand);
    k_select<<<1, 256, 0, stream>>>(cand, ccnt, basec, svals, sums, sumsqs, coef);
    k_kde<<<dim3(64, 32), 256, 0, stream>>>(Xq, Xf, nmu2, coef, out);
}

// Round 3
// 134.578 us; speedup vs baseline: 1.5663x; 1.5014x over previous
//
#include <hip/hip_runtime.h>
#include <hip/hip_bf16.h>
#include <math.h>

// Problem constants (fixed shapes from setup_inputs)
#define BB 4
#define MM 4096
#define DD 32
#define NPTS (BB*MM)        // 16384 fit points
#define TOTELEM (NPTS*DD)   // 524288 floats in X_fit
#define NBINS 4096
#define CAP 1024            // candidates per quantile bin (~163 expected)

// ws layout (bytes)
#define HIST_OFF   0        // 4096 u32
#define SUM_OFF    16384    // 4 f32
#define SUMSQ_OFF  16400    // 4 f32
#define CCNT_OFF   16416    // 4 u32
#define TBIN_OFF   16432    // 4 i32
#define BASE_OFF   16448    // 4 u32
#define SVAL_OFF   16464    // 4 f32
#define COEF_OFF   16480    // 4 f32
#define ZERO_BYTES 16512
#define CAND_OFF   16512                  // 4*1024 f32 = 16 KB
#define NMU2_OFF   (CAND_OFF + 16384)     // 16384 f32 = 64 KB
#define NX2_OFF    (NMU2_OFF + 65536)     // 16384 f32 = 64 KB
// total ws use: ~160 KB

typedef short bf16x8 __attribute__((ext_vector_type(8)));
typedef float f32x4  __attribute__((ext_vector_type(4)));

__device__ __forceinline__ int bin_of(float x) {
    int b = (int)floorf((x + 2.0f) * 1024.0f);
    return b < 0 ? 0 : (b > (NBINS - 1) ? (NBINS - 1) : b);
}

// split 8 fp32 -> hi/lo bf16 fragments (RNE both stages; uses v_cvt_pk_bf16_f32)
__device__ __forceinline__ void cvt8(float4 a, float4 b, bf16x8* hi, bf16x8* lo) {
    union U { bf16x8 v; __hip_bfloat162 p[4]; };
    U H, L;
    float2 x0 = make_float2(a.x, a.y), x1 = make_float2(a.z, a.w);
    float2 x2 = make_float2(b.x, b.y), x3 = make_float2(b.z, b.w);
    float2 xs[4] = {x0, x1, x2, x3};
    #pragma unroll
    for (int i = 0; i < 4; i++) {
        __hip_bfloat162 h = __float22bfloat162_rn(xs[i]);
        float2 hf = __bfloat1622float2(h);
        float2 l  = make_float2(xs[i].x - hf.x, xs[i].y - hf.y);
        H.p[i] = h;
        L.p[i] = __float22bfloat162_rn(l);
    }
    *hi = H.v; *lo = L.v;
}

// K1: fused prep.
// blocks 0..255  : X_fit quarter-points -> hist, per-batch sum/sumsq, nmu2
// blocks 256..511: X_query quarter-points -> nx2
__global__ __launch_bounds__(256) void k_prep(
    const float* __restrict__ Xq, const float* __restrict__ Xf,
    unsigned int* __restrict__ hist, float* __restrict__ sums,
    float* __restrict__ sumsqs, float* __restrict__ nmu2,
    float* __restrict__ nx2)
{
    __shared__ unsigned int lh[NBINS];
    __shared__ float rs[256], rs2[256];
    int tid = threadIdx.x;

    if (blockIdx.x >= 256) {
        // ---- query side: nx2 only ----
        int t = (blockIdx.x - 256) * 256 + tid;        // quarter-point index
        const float4* src = (const float4*)Xq + (size_t)t * 2;
        float4 v0 = src[0], v1 = src[1];
        float xs[8] = {v0.x, v0.y, v0.z, v0.w, v1.x, v1.y, v1.z, v1.w};
        float s2 = 0.f;
        #pragma unroll
        for (int c = 0; c < 8; c++) s2 = fmaf(xs[c], xs[c], s2);
        float r = s2;
        r += __shfl_xor(r, 1);
        r += __shfl_xor(r, 2);
        if ((t & 3) == 0) nx2[t >> 2] = r;
        return;
    }

    // ---- fit side ----
    for (int i = tid; i < NBINS; i += 256) lh[i] = 0;
    __syncthreads();

    int t = blockIdx.x * 256 + tid;          // 0..65535, quarter-point index
    int b = blockIdx.x >> 6;                 // 64 blocks per batch
    const float4* src = (const float4*)Xf + (size_t)t * 2;
    float4 v0 = src[0], v1 = src[1];
    float xs[8] = {v0.x, v0.y, v0.z, v0.w, v1.x, v1.y, v1.z, v1.w};
    float s = 0.f, s2 = 0.f;
    #pragma unroll
    for (int c = 0; c < 8; c++) {
        float x = xs[c];
        s += x;
        s2 = fmaf(x, x, s2);
        atomicAdd(&lh[bin_of(x)], 1u);
    }
    float r = s2;
    r += __shfl_xor(r, 1);
    r += __shfl_xor(r, 2);
    if ((t & 3) == 0) nmu2[t >> 2] = r;

    rs[tid] = s; rs2[tid] = s2;
    __syncthreads();
    for (int off = 128; off > 0; off >>= 1) {
        if (tid < off) { rs[tid] += rs[tid + off]; rs2[tid] += rs2[tid + off]; }
        __syncthreads();
    }
    if (tid == 0) { atomicAdd(&sums[b], rs[0]); atomicAdd(&sumsqs[b], rs2[0]); }
    __syncthreads();
    for (int i = tid; i < NBINS; i += 256)
        if (lh[i]) atomicAdd(&hist[i], lh[i]);
}

// K2: scan histogram, locate bin + cumulative base for each target rank
__global__ __launch_bounds__(256) void k_findbins(
    const unsigned int* __restrict__ hist, int* __restrict__ tbin,
    unsigned int* __restrict__ basec)
{
    __shared__ unsigned int chunk[256];
    int tid = threadIdx.x;
    unsigned int s = 0;
    for (int i = 0; i < 16; i++) s += hist[tid * 16 + i];
    chunk[tid] = s;
    __syncthreads();
    if (tid == 0) {
        unsigned int run = 0;
        for (int i = 0; i < 256; i++) { unsigned int t = chunk[i]; chunk[i] = run; run += t; }
    }
    __syncthreads();
    const unsigned int ranks[4] = {131071u, 131072u, 393215u, 393216u};
    unsigned int cum = chunk[tid];
    for (int i = 0; i < 16; i++) {
        int bin = tid * 16 + i;
        unsigned int c = hist[bin];
        #pragma unroll
        for (int r = 0; r < 4; r++) {
            if (cum <= ranks[r] && ranks[r] < cum + c) { tbin[r] = bin; basec[r] = cum; }
        }
        cum += c;
    }
}

// K3: collect candidate values falling in each target bin
__global__ __launch_bounds__(256) void k_collect(
    const float* __restrict__ Xf, const int* __restrict__ tbin,
    unsigned int* __restrict__ ccnt, float* __restrict__ cand)
{
    int gid = blockIdx.x * 256 + threadIdx.x;   // 131072 threads, 4 floats each
    float4 v = ((const float4*)Xf)[gid];
    int t0 = tbin[0], t1 = tbin[1], t2 = tbin[2], t3 = tbin[3];
    float xs[4] = {v.x, v.y, v.z, v.w};
    #pragma unroll
    for (int c = 0; c < 4; c++) {
        int bin = bin_of(xs[c]);
        int tb[4] = {t0, t1, t2, t3};
        #pragma unroll
        for (int r = 0; r < 4; r++) {
            if (bin == tb[r]) {
                unsigned int pos = atomicAdd(&ccnt[r], 1u);
                if (pos < CAP) cand[r * CAP + pos] = xs[c];
            }
        }
    }
}

// K4: exact selection within candidates, then bandwidth -> coef[b] = log2(e)/bw
__global__ __launch_bounds__(256) void k_select(
    const float* __restrict__ cand, const unsigned int* __restrict__ ccnt,
    const unsigned int* __restrict__ basec, float* svals,
    const float* __restrict__ sums, const float* __restrict__ sumsqs,
    float* __restrict__ coef)
{
    __shared__ float cv[CAP];
    const unsigned int ranks[4] = {131071u, 131072u, 393215u, 393216u};
    int tid = threadIdx.x;
    for (int r = 0; r < 4; r++) {
        unsigned int C = ccnt[r]; if (C > CAP) C = CAP;
        unsigned int k = ranks[r] - basec[r];
        for (unsigned int i = tid; i < C; i += 256) cv[i] = cand[r * CAP + i];
        __syncthreads();
        for (unsigned int i = tid; i < C; i += 256) {
            float v = cv[i];
            unsigned int lt = 0, eq = 0;
            for (unsigned int j = 0; j < C; j++) {
                float w = cv[j];
                lt += (w < v) ? 1u : 0u;
                eq += (w == v) ? 1u : 0u;
            }
            if (lt <= k && k < lt + eq) svals[r] = v;
        }
        __syncthreads();
    }
    if (tid == 0) {
        float s0 = svals[0], s1 = svals[1], s2 = svals[2], s3 = svals[3];
        double q25 = (double)s0 + 0.75 * ((double)s1 - (double)s0);
        double q75 = (double)s2 + 0.25 * ((double)s3 - (double)s2);
        double q = q75 - q25;
        for (int b = 0; b < BB; b++) {
            double n = (double)(MM * DD);
            double sm = (double)sums[b], sq = (double)sumsqs[b];
            double var = (sq - sm * sm / n) / (n - 1.0);
            double sd = sqrt(var);
            double mn = sd < q / 1.34 ? sd : q / 1.34;
            double bw = 0.9 * mn / 5.278031643091577;   // 4096**0.2
            coef[b] = (float)(1.4426950408889634 / bw); // log2(e)/bw
        }
    }
}

// K5: MFMA KDE. Wave = 4 q-tiles (64 queries) x 256 m-points.
// Split-bf16: dot = Ah*Bh + Ah*Bl + Al*Bh (3x mfma_f32_16x16x32_bf16).
// A/B frag: lane&15 = row index, (lane>>4)*8 = k offset (row-major K-contig).
// C/D: col = lane&15 (m-point), row = (lane>>4)*4 + reg (query).
__global__ __launch_bounds__(256) void k_kde(
    const float* __restrict__ Xq, const float* __restrict__ Xf,
    const float* __restrict__ nmu2, const float* __restrict__ nx2,
    const float* __restrict__ coef, float* __restrict__ out)
{
    int tid = threadIdx.x;
    int lane = tid & 63;
    int wid = blockIdx.x * 4 + (tid >> 6);   // 0..4095
    int b   = wid >> 10;
    int rem = wid & 1023;
    int q0  = (rem >> 4) * 64;               // query group base (64 queries)
    int m0  = (rem & 15) * 256;              // m chunk base (256 points)
    int l16 = lane & 15, quad = lane >> 4;

    const float c  = coef[b];
    const float c2 = 2.0f * c;

    // A fragments (4 q-tiles), hi+lo
    const float* Qb = Xq + ((size_t)b * MM + q0) * DD;
    bf16x8 Ah[4], Al[4];
    #pragma unroll
    for (int t = 0; t < 4; t++) {
        const float4* p = (const float4*)(Qb + ((t * 16 + l16) * DD + quad * 8));
        cvt8(p[0], p[1], &Ah[t], &Al[t]);
    }
    // qz[t][r] = -c * nx2[query(t, quad, r)]
    const float* nxb = nx2 + b * MM + q0;
    float qz[4][4];
    #pragma unroll
    for (int t = 0; t < 4; t++)
        #pragma unroll
        for (int r = 0; r < 4; r++)
            qz[t][r] = -c * nxb[t * 16 + quad * 4 + r];

    float acc[4][4];
    #pragma unroll
    for (int t = 0; t < 4; t++)
        #pragma unroll
        for (int r = 0; r < 4; r++) acc[t][r] = 0.f;

    const float* Fb  = Xf  + ((size_t)b * MM + m0) * DD;
    const float* nmb = nmu2 + b * MM + m0;

    for (int mt = 0; mt < 16; ++mt) {
        const float4* p = (const float4*)(Fb + ((mt * 16 + l16) * DD + quad * 8));
        float4 f0 = p[0], f1 = p[1];
        bf16x8 Bh, Bl;
        cvt8(f0, f1, &Bh, &Bl);
        float w = -c * nmb[mt * 16 + l16];
        #pragma unroll
        for (int t = 0; t < 4; t++) {
            f32x4 d = {0.f, 0.f, 0.f, 0.f};
            d = __builtin_amdgcn_mfma_f32_16x16x32_bf16(Al[t], Bh, d, 0, 0, 0);
            d = __builtin_amdgcn_mfma_f32_16x16x32_bf16(Ah[t], Bl, d, 0, 0, 0);
            d = __builtin_amdgcn_mfma_f32_16x16x32_bf16(Ah[t], Bh, d, 0, 0, 0);
            #pragma unroll
            for (int r = 0; r < 4; r++) {
                float arg = fmaf(c2, d[r], qz[t][r] + w);
                acc[t][r] += exp2f(arg);
            }
        }
    }

    // reduce each acc[t][r] across the 16 lanes of the quad group (sum over m cols)
    #pragma unroll
    for (int t = 0; t < 4; t++)
        #pragma unroll
        for (int r = 0; r < 4; r++) {
            float v = acc[t][r];
            v += __shfl_xor(v, 1);
            v += __shfl_xor(v, 2);
            v += __shfl_xor(v, 4);
            v += __shfl_xor(v, 8);
            acc[t][r] = v;
        }

    // lane l16 writes (t,r) = (l16>>2, l16&3) for its quad's row block
    int ts = l16 >> 2, rs = l16 & 3;
    float val = 0.f;
    #pragma unroll
    for (int t = 0; t < 4; t++)
        #pragma unroll
        for (int r = 0; r < 4; r++)
            if (t == ts && r == rs) val = acc[t][r];
    atomicAdd(&out[b * MM + q0 + ts * 16 + quad * 4 + rs], val);
}

extern "C" void kernel_launch(void* const* d_in, const int* in_sizes, int n_in,
                              void* d_out, int out_size, void* d_ws, size_t ws_size,
                              hipStream_t stream) {
    const float* Xq = (const float*)d_in[0];
    const float* Xf = (const float*)d_in[1];
    float* out = (float*)d_out;
    char* ws = (char*)d_ws;

    unsigned int* hist  = (unsigned int*)(ws + HIST_OFF);
    float* sums         = (float*)(ws + SUM_OFF);
    float* sumsqs       = (float*)(ws + SUMSQ_OFF);
    unsigned int* ccnt  = (unsigned int*)(ws + CCNT_OFF);
    int* tbin           = (int*)(ws + TBIN_OFF);
    unsigned int* basec = (unsigned int*)(ws + BASE_OFF);
    float* svals        = (float*)(ws + SVAL_OFF);
    float* coef         = (float*)(ws + COEF_OFF);
    float* cand         = (float*)(ws + CAND_OFF);
    float* nmu2         = (float*)(ws + NMU2_OFF);
    float* nx2          = (float*)(ws + NX2_OFF);

    hipMemsetAsync(ws, 0, ZERO_BYTES, stream);
    hipMemsetAsync(d_out, 0, (size_t)out_size * sizeof(float), stream);

    k_prep<<<512, 256, 0, stream>>>(Xq, Xf, hist, sums, sumsqs, nmu2, nx2);
    k_findbins<<<1, 256, 0, stream>>>(hist, tbin, basec);
    k_collect<<<TOTELEM / (256 * 4), 256, 0, stream>>>(Xf, tbin, ccnt, cand);
    k_select<<<1, 256, 0, stream>>>(cand, ccnt, basec, svals, sums, sumsqs, coef);
    k_kde<<<dim3(1024), 256, 0, stream>>>(Xq, Xf, nmu2, nx2, coef, out);
}